// Round 24
// baseline (72.267 us; speedup 1.0000x reference)
//
#include <hip/hip_runtime.h>

typedef float v4f   __attribute__((ext_vector_type(4)));
typedef float f32x4 __attribute__((ext_vector_type(4)));
typedef _Float16 h4 __attribute__((ext_vector_type(4)));
typedef _Float16 h8 __attribute__((ext_vector_type(8)));

#define HH 512
#define WW 512
#define NPLANES 96
#define NSTRIP 32
#define NUNIT (NPLANES * NSTRIP)   // 3072 waves, one per (plane,strip)
#define WPB 2                      // independent waves per block (no barriers)
#define NBLK (NUNIT / WPB)         // 1536 blocks
#define C1V 1e-4f
#define C2V 9e-4f
#define EPSV 1e-8f
#define NPIX 25165824.0f           // 32*3*512*512

// per-wave LDS H-ring: [q 5][slot 5][col 16][48 B]; slots 0..3 ring, slot 4 = zeros
#define SLOT_B 768                 // 16 cols * 48 B
#define Q_B    3840                // 5 slots
#define WAVE_B 19200
#define LDS_B  (WPB * WAVE_B)      // 38400

#define MF(A, B) __builtin_amdgcn_mfma_f32_16x16x32_f16((A), (B), zf, 0, 0, 0)

// 11-way select from named weight scalars (no arrays -> no scratch)
#define SELW(DST, IX) { const int ix_ = (IX); float r_ = 0.f; \
  r_ = (ix_ == 0) ? wv0 : r_;  r_ = (ix_ == 1) ? wv1 : r_; \
  r_ = (ix_ == 2) ? wv2 : r_;  r_ = (ix_ == 3) ? wv3 : r_; \
  r_ = (ix_ == 4) ? wv4 : r_;  r_ = (ix_ == 5) ? wv5 : r_; \
  r_ = (ix_ == 6) ? wv6 : r_;  r_ = (ix_ == 7) ? wv7 : r_; \
  r_ = (ix_ == 8) ? wv8 : r_;  r_ = (ix_ == 9) ? wv9 : r_; \
  r_ = (ix_ == 10) ? wv10 : r_; DST = r_; }

// f32 -> f16 pack via RNE casts (v_cvt_f16_f32), unbiased
#define PACK8(DST, F0,F1,F2,F3,F4,F5,F6,F7) \
  DST = (h8){(_Float16)(F0),(_Float16)(F1),(_Float16)(F2),(_Float16)(F3), \
             (_Float16)(F4),(_Float16)(F5),(_Float16)(F6),(_Float16)(F7)};

// 4 independent accumulators (break the serial fmaf+rcp chain)
#define EPX(M) { \
  const float mux_ = mx[M], muy_ = my[M]; \
  const float mx2_ = mux_ * mux_, my2_ = muy_ * muy_, mxy_ = mux_ * muy_; \
  const float sx2_ = vx2[M] - mx2_, sy2_ = vy2[M] - my2_, sxy_ = vxy[M] - mxy_; \
  const float num_ = fmaf(2.f, mxy_, C1V) * fmaf(2.f, sxy_, C2V); \
  const float den_ = (mx2_ + my2_ + C1V) * (sx2_ + sy2_ + C2V) + EPSV; \
  acc##M = fmaf(num_, __builtin_amdgcn_rcpf(den_), acc##M); }

// V for out-chunk TAU: lane (n,s) reads 8 rows of col n from H chunk
// ch = TAU-1+{0,1,1,2} (ring slot ch&3; zero slot 4 outside image).
#define VSTEP(TAU) { \
  const int tau_ = (TAU); \
  const int ch_ = tau_ - 1 + ((s + 1) >> 1); \
  const int slot_ = ((unsigned)ch_ < 32u) ? (ch_ & 3) : 4; \
  const char* rb_ = wlds + slot_ * SLOT_B + rByte; \
  const h8 bx  = *(const h8*)(rb_); \
  const h8 by  = *(const h8*)(rb_ + Q_B); \
  const h8 bx2 = *(const h8*)(rb_ + 2 * Q_B); \
  const h8 by2 = *(const h8*)(rb_ + 3 * Q_B); \
  const h8 bxy = *(const h8*)(rb_ + 4 * Q_B); \
  __builtin_amdgcn_s_setprio(1); \
  const f32x4 mx  = MF(Wf, bx);  const f32x4 my  = MF(Wf, by); \
  const f32x4 vx2 = MF(Wf, bx2); const f32x4 vy2 = MF(Wf, by2); \
  const f32x4 vxy = MF(Wf, bxy); \
  __builtin_amdgcn_s_setprio(0); \
  EPX(0) EPX(1) EPX(2) EPX(3) }

// H-only step for chunk T: consume CUR raw regs, prefetch chunk T+2 into NXT,
// 5 H-MFMA (weight-killed cols -> genuine zeros), store ring slot T&3.
#define HSTEP(T, CXA,CXB,CYA,CYB, NXA,NXB,NYA,NYB) { \
  const int t_ = (T); \
  if (t_ < 30) { \
    NXA = *(const v4f*)pXa; NXB = *(const v4f*)pXb; \
    NYA = *(const v4f*)pYa; NYB = *(const v4f*)pYb; \
    pXa += 16 * WW; pXb += 16 * WW; pYa += 16 * WW; pYb += 16 * WW; \
  } \
  h8 ax, ay; \
  PACK8(ax, CXA[0],CXA[1],CXA[2],CXA[3], CXB[0],CXB[1],CXB[2],CXB[3]) \
  PACK8(ay, CYA[0],CYA[1],CYA[2],CYA[3], CYB[0],CYB[1],CYB[2],CYB[3]) \
  const h8 ax2 = ax * ax, ay2 = ay * ay, axy = ax * ay; \
  __builtin_amdgcn_s_setprio(1); \
  const f32x4 chx  = MF(ax,  WfH); const f32x4 chy  = MF(ay,  WfH); \
  const f32x4 chx2 = MF(ax2, WfH); const f32x4 chy2 = MF(ay2, WfH); \
  const f32x4 chxy = MF(axy, WfH); \
  __builtin_amdgcn_s_setprio(0); \
  { char* wb_ = wlds + (t_ & 3) * SLOT_B + wByte; \
    *(h4*)(wb_)         = (h4){(_Float16)chx[0], (_Float16)chx[1], (_Float16)chx[2], (_Float16)chx[3]}; \
    *(h4*)(wb_ + Q_B)   = (h4){(_Float16)chy[0], (_Float16)chy[1], (_Float16)chy[2], (_Float16)chy[3]}; \
    *(h4*)(wb_ + 2*Q_B) = (h4){(_Float16)chx2[0],(_Float16)chx2[1],(_Float16)chx2[2],(_Float16)chx2[3]}; \
    *(h4*)(wb_ + 3*Q_B) = (h4){(_Float16)chy2[0],(_Float16)chy2[1],(_Float16)chy2[2],(_Float16)chy2[3]}; \
    *(h4*)(wb_ + 4*Q_B) = (h4){(_Float16)chxy[0],(_Float16)chxy[1],(_Float16)chxy[2],(_Float16)chxy[3]}; } }

__global__ __launch_bounds__(64 * WPB)
void ssim_main(const float* __restrict__ x, const float* __restrict__ y,
               float* __restrict__ partial)
{
  __shared__ __attribute__((aligned(16))) char lds[LDS_B];

  const int l = threadIdx.x & 63;
  const int wid = threadIdx.x >> 6;   // 2 independent waves per block
  const int n = l & 15;               // H: image row in chunk; V: out col
  const int s = l >> 4;               // k quadrant

  // XCD swizzle: 192 consecutive blocks per XCD; waves take adjacent units
  const int wg = blockIdx.x;
  const int swz = (wg & 7) * (NBLK / 8) + (wg >> 3);
  const int unit = swz * WPB + wid;   // 0..3071
  const int plane = unit >> 5;
  const int strip = unit & 31;
  const int C0 = strip * 16;

  char* wlds = lds + wid * WAVE_B;

  const float* xp = x + (size_t)plane * (HH * WW);
  const float* yp = y + (size_t)plane * (HH * WW);

  // Gaussian window (exact reference formula), named scalars -> SGPRs
  float wv0, wv1, wv2, wv3, wv4, wv5, wv6, wv7, wv8, wv9, wv10;
#define WINIT(k) wv##k = expf(-((float)((k - 5) * (k - 5))) / 4.5f);
  WINIT(0) WINIT(1) WINIT(2) WINIT(3) WINIT(4) WINIT(5)
  WINIT(6) WINIT(7) WINIT(8) WINIT(9) WINIT(10)
#undef WINIT
  const float inv_ = 1.f / (wv0 + wv1 + wv2 + wv3 + wv4 + wv5 + wv6 + wv7 + wv8 + wv9 + wv10);
#define WNORM(k) wv##k = __int_as_float(__builtin_amdgcn_readfirstlane(__float_as_int(wv##k * inv_)));
  WNORM(0) WNORM(1) WNORM(2) WNORM(3) WNORM(4) WNORM(5)
  WNORM(6) WNORM(7) WNORM(8) WNORM(9) WNORM(10)
#undef WNORM

  const f32x4 zf = {0.f, 0.f, 0.f, 0.f};

  // shared banded weight fragment: W[k][i] = w[k-i-3] (B in H, A in V)
  h8 Wf;
  {
    const int kb = 8 * s;
    float b0,b1,b2,b3,b4,b5,b6,b7;
    SELW(b0, kb + 0 - n - 3) SELW(b1, kb + 1 - n - 3)
    SELW(b2, kb + 2 - n - 3) SELW(b3, kb + 3 - n - 3)
    SELW(b4, kb + 4 - n - 3) SELW(b5, kb + 5 - n - 3)
    SELW(b6, kb + 6 - n - 3) SELW(b7, kb + 7 - n - 3)
    PACK8(Wf, b0,b1,b2,b3,b4,b5,b6,b7)
  }

  // H raw-tap window: cols C0-8+8s..+7; fully-outside groups weight-killed
  const int cb = C0 - 8 + 8 * s;
  const bool kill = (cb < 0) || (cb >= WW);
  h8 WfH = Wf;
  if (kill) WfH = (h8)(_Float16)0.f;
  const int ca = kill ? 0 : cb;

  const int wByte = n * 48 + 8 * s;                    // store: col n, rows 4s..4s+3
  const int rByte = n * 48 + 16 * ((s + 1) & 1);       // read: col n, rowbase {8,0,8,0}

  // zero-slot init (slot 4, all 5 quantities) -- per wave, no barrier needed
  #pragma unroll
  for (int q = 0; q < 5; ++q)
    #pragma unroll
    for (int j = 0; j < 3; ++j)
      *(unsigned*)(wlds + q * Q_B + 4 * SLOT_B + 4 * (l + 64 * j)) = 0u;

  float acc0 = 0.f, acc1 = 0.f, acc2 = 0.f, acc3 = 0.f;

  // raw register sets: E = even chunks, O = odd chunks; two of each (prefetch d=2)
  v4f EXA0, EXB0, EYA0, EYB0, EXA1, EXB1, EYA1, EYB1;
  v4f OXA0, OXB0, OYA0, OYB0, OXA1, OXB1, OYA1, OYB1;

  // prologue: chunk 0 -> E0, chunk 1 -> O0; streaming pointers start at chunk 2
  EXA0 = *(const v4f*)(xp + n * WW + ca);
  EXB0 = *(const v4f*)(xp + n * WW + ca + 4);
  EYA0 = *(const v4f*)(yp + n * WW + ca);
  EYB0 = *(const v4f*)(yp + n * WW + ca + 4);
  OXA0 = *(const v4f*)(xp + (16 + n) * WW + ca);
  OXB0 = *(const v4f*)(xp + (16 + n) * WW + ca + 4);
  OYA0 = *(const v4f*)(yp + (16 + n) * WW + ca);
  OYB0 = *(const v4f*)(yp + (16 + n) * WW + ca + 4);
  const float* pXa = xp + (32 + n) * WW + ca;
  const float* pXb = pXa + 4;
  const float* pYa = yp + (32 + n) * WW + ca;
  const float* pYb = pYa + 4;

  // u=0 peeled: H(0), H(1), V(0)
  HSTEP(0, EXA0,EXB0,EYA0,EYB0, EXA1,EXB1,EYA1,EYB1)
  HSTEP(1, OXA0,OXB0,OYA0,OYB0, OXA1,OXB1,OYA1,OYB1)
  VSTEP(0)

  // u = 1..14 (7 double-iterations): per u -> H(2u), H(2u+1), V(2u-1), V(2u)
  #pragma unroll 1
  for (int w = 0; w < 7; ++w) {
    const int u1 = 2 * w + 1;
    HSTEP(2 * u1,     EXA1,EXB1,EYA1,EYB1, EXA0,EXB0,EYA0,EYB0)
    HSTEP(2 * u1 + 1, OXA1,OXB1,OYA1,OYB1, OXA0,OXB0,OYA0,OYB0)
    VSTEP(2 * u1 - 1)
    VSTEP(2 * u1)
    const int u2 = 2 * w + 2;
    HSTEP(2 * u2,     EXA0,EXB0,EYA0,EYB0, EXA1,EXB1,EYA1,EYB1)
    HSTEP(2 * u2 + 1, OXA0,OXB0,OYA0,OYB0, OXA1,OXB1,OYA1,OYB1)
    VSTEP(2 * u2 - 1)
    VSTEP(2 * u2)
  }
  // u=15: H(30), H(31), V(29), V(30); tail V(31)
  HSTEP(30, EXA1,EXB1,EYA1,EYB1, EXA0,EXB0,EYA0,EYB0)
  HSTEP(31, OXA1,OXB1,OYA1,OYB1, OXA0,OXB0,OYA0,OYB0)
  VSTEP(29)
  VSTEP(30)
  VSTEP(31)

  // wave reduction -> per-wave partial (no barriers)
  float acc = (acc0 + acc1) + (acc2 + acc3);
  #pragma unroll
  for (int off = 32; off > 0; off >>= 1) acc += __shfl_down(acc, off);
  if (l == 0) partial[unit] = acc;
}

__global__ void finalize_kernel(const float* __restrict__ partial, float* __restrict__ out)
{
  __shared__ float s4[4];
  float a = 0.f;
  for (int i = threadIdx.x; i < NUNIT; i += 256) a += partial[i];
  #pragma unroll
  for (int off = 32; off > 0; off >>= 1) a += __shfl_down(a, off);
  if ((threadIdx.x & 63) == 0) s4[threadIdx.x >> 6] = a;
  __syncthreads();
  if (threadIdx.x == 0) out[0] = 1.f - (s4[0] + s4[1] + s4[2] + s4[3]) * (1.f / NPIX);
}

extern "C" void kernel_launch(void* const* d_in, const int* in_sizes, int n_in,
                              void* d_out, int out_size, void* d_ws, size_t ws_size,
                              hipStream_t stream)
{
  const float* x = (const float*)d_in[0];
  const float* y = (const float*)d_in[1];
  float* ws = (float*)d_ws;
  float* out = (float*)d_out;

  hipLaunchKernelGGL(ssim_main, dim3(NBLK), dim3(64 * WPB), 0, stream, x, y, ws);
  hipLaunchKernelGGL(finalize_kernel, dim3(1), dim3(256), 0, stream, ws, out);
}

// Round 25
// 60.036 us; speedup vs baseline: 1.2037x; 1.2037x over previous
//
#include <hip/hip_runtime.h>

typedef float v4f   __attribute__((ext_vector_type(4)));
typedef float f32x4 __attribute__((ext_vector_type(4)));
typedef _Float16 h4 __attribute__((ext_vector_type(4)));
typedef _Float16 h8 __attribute__((ext_vector_type(8)));

#define HH 512
#define WW 512
#define NPLANES 96
#define NSTRIP 32
#define NBLK (NPLANES * NSTRIP)   // 3072
#define C1V 1e-4f
#define C2V 9e-4f
#define EPSV 1e-8f
#define NPIX 25165824.0f          // 32*3*512*512

// LDS H-ring: [q 5][slot 5][col 16][48 B]; slots 0..3 ring, slot 4 = zeros.
#define SLOT_B 768                // 16 cols * 48 B
#define Q_B    3840               // 5 slots
#define LDS_B  19200

#define MF(A, B) __builtin_amdgcn_mfma_f32_16x16x32_f16((A), (B), zf, 0, 0, 0)

// 11-way select from named weight scalars (no arrays -> no scratch)
#define SELW(DST, IX) { const int ix_ = (IX); float r_ = 0.f; \
  r_ = (ix_ == 0) ? wv0 : r_;  r_ = (ix_ == 1) ? wv1 : r_; \
  r_ = (ix_ == 2) ? wv2 : r_;  r_ = (ix_ == 3) ? wv3 : r_; \
  r_ = (ix_ == 4) ? wv4 : r_;  r_ = (ix_ == 5) ? wv5 : r_; \
  r_ = (ix_ == 6) ? wv6 : r_;  r_ = (ix_ == 7) ? wv7 : r_; \
  r_ = (ix_ == 8) ? wv8 : r_;  r_ = (ix_ == 9) ? wv9 : r_; \
  r_ = (ix_ == 10) ? wv10 : r_; DST = r_; }

// f32 -> f16 pack via RNE casts (v_cvt_f16_f32), unbiased
#define PACK8(DST, F0,F1,F2,F3,F4,F5,F6,F7) \
  DST = (h8){(_Float16)(F0),(_Float16)(F1),(_Float16)(F2),(_Float16)(F3), \
             (_Float16)(F4),(_Float16)(F5),(_Float16)(F6),(_Float16)(F7)};

// 4 independent accumulators (break the serial fmaf+rcp chain)
#define EPX(M) { \
  const float mux_ = mx[M], muy_ = my[M]; \
  const float mx2_ = mux_ * mux_, my2_ = muy_ * muy_, mxy_ = mux_ * muy_; \
  const float sx2_ = vx2[M] - mx2_, sy2_ = vy2[M] - my2_, sxy_ = vxy[M] - mxy_; \
  const float num_ = fmaf(2.f, mxy_, C1V) * fmaf(2.f, sxy_, C2V); \
  const float den_ = (mx2_ + my2_ + C1V) * (sx2_ + sy2_ + C2V) + EPSV; \
  acc##M = fmaf(num_, __builtin_amdgcn_rcpf(den_), acc##M); }

// V for out-chunk TAU: K window = H rows [16*TAU-8, 16*TAU+24); lane (n,s)
// needs 8 rows of col n from H chunk ch_ (zero slot if outside the image).
#define VSTEP(TAU) { \
  const int tau_ = (TAU); \
  const int ch_ = tau_ - 1 + ((s + 1) >> 1); \
  const int slot_ = ((unsigned)ch_ < 32u) ? (ch_ & 3) : 4; \
  const char* rb_ = lds + slot_ * SLOT_B + rByte; \
  const h8 bx  = *(const h8*)(rb_); \
  const h8 by  = *(const h8*)(rb_ + Q_B); \
  const h8 bx2 = *(const h8*)(rb_ + 2 * Q_B); \
  const h8 by2 = *(const h8*)(rb_ + 3 * Q_B); \
  const h8 bxy = *(const h8*)(rb_ + 4 * Q_B); \
  __builtin_amdgcn_s_setprio(1); \
  const f32x4 mx  = MF(Wf, bx);  const f32x4 my  = MF(Wf, by); \
  const f32x4 vx2 = MF(Wf, bx2); const f32x4 vy2 = MF(Wf, by2); \
  const f32x4 vxy = MF(Wf, bxy); \
  __builtin_amdgcn_s_setprio(0); \
  EPX(0) EPX(1) EPX(2) EPX(3) }

// H-only step for chunk T: consume CUR raw regs, prefetch chunk T+2 into NXT
// (distance-2: consumed next iteration), 5 H-MFMA, store ring slot T&3.
// V work is NOT chained here -- it runs grouped after the two H's (ILP).
#define HSTEP(T, CXA,CXB,CYA,CYB, NXA,NXB,NYA,NYB) { \
  const int t_ = (T); \
  if (t_ < 30) { \
    NXA = *(const v4f*)pXa; NXB = *(const v4f*)pXb; \
    NYA = *(const v4f*)pYa; NYB = *(const v4f*)pYb; \
    pXa += 16 * WW; pXb += 16 * WW; pYa += 16 * WW; pYb += 16 * WW; \
  } \
  h8 ax, ay; \
  PACK8(ax, CXA[0],CXA[1],CXA[2],CXA[3], CXB[0],CXB[1],CXB[2],CXB[3]) \
  PACK8(ay, CYA[0],CYA[1],CYA[2],CYA[3], CYB[0],CYB[1],CYB[2],CYB[3]) \
  const h8 ax2 = ax * ax, ay2 = ay * ay, axy = ax * ay; \
  __builtin_amdgcn_s_setprio(1); \
  const f32x4 chx  = MF(ax,  WfH); const f32x4 chy  = MF(ay,  WfH); \
  const f32x4 chx2 = MF(ax2, WfH); const f32x4 chy2 = MF(ay2, WfH); \
  const f32x4 chxy = MF(axy, WfH); \
  __builtin_amdgcn_s_setprio(0); \
  { char* wb_ = lds + (t_ & 3) * SLOT_B + wByte; \
    *(h4*)(wb_)         = (h4){(_Float16)chx[0], (_Float16)chx[1], (_Float16)chx[2], (_Float16)chx[3]}; \
    *(h4*)(wb_ + Q_B)   = (h4){(_Float16)chy[0], (_Float16)chy[1], (_Float16)chy[2], (_Float16)chy[3]}; \
    *(h4*)(wb_ + 2*Q_B) = (h4){(_Float16)chx2[0],(_Float16)chx2[1],(_Float16)chx2[2],(_Float16)chx2[3]}; \
    *(h4*)(wb_ + 3*Q_B) = (h4){(_Float16)chy2[0],(_Float16)chy2[1],(_Float16)chy2[2],(_Float16)chy2[3]}; \
    *(h4*)(wb_ + 4*Q_B) = (h4){(_Float16)chxy[0],(_Float16)chxy[1],(_Float16)chxy[2],(_Float16)chxy[3]}; } }

__global__ __launch_bounds__(64)
void ssim_main(const float* __restrict__ x, const float* __restrict__ y,
               float* __restrict__ partial)
{
  __shared__ __attribute__((aligned(16))) char lds[LDS_B];

  const int l = threadIdx.x;
  const int n = l & 15;     // H: A-row (image row in chunk); V: B/D col (out col)
  const int s = l >> 4;     // k quadrant (8 consecutive k)

  // XCD swizzle: each XCD gets 384 consecutive (plane,strip) units
  const int wg = blockIdx.x;
  const int swz = (wg & 7) * (NBLK / 8) + (wg >> 3);
  const int plane = swz >> 5;
  const int strip = swz & 31;
  const int C0 = strip * 16;

  const float* xp = x + (size_t)plane * (HH * WW);
  const float* yp = y + (size_t)plane * (HH * WW);

  // Gaussian window (exact reference formula), named scalars -> SGPRs
  float wv0, wv1, wv2, wv3, wv4, wv5, wv6, wv7, wv8, wv9, wv10;
#define WINIT(k) wv##k = expf(-((float)((k - 5) * (k - 5))) / 4.5f);
  WINIT(0) WINIT(1) WINIT(2) WINIT(3) WINIT(4) WINIT(5)
  WINIT(6) WINIT(7) WINIT(8) WINIT(9) WINIT(10)
#undef WINIT
  const float inv_ = 1.f / (wv0 + wv1 + wv2 + wv3 + wv4 + wv5 + wv6 + wv7 + wv8 + wv9 + wv10);
#define WNORM(k) wv##k = __int_as_float(__builtin_amdgcn_readfirstlane(__float_as_int(wv##k * inv_)));
  WNORM(0) WNORM(1) WNORM(2) WNORM(3) WNORM(4) WNORM(5)
  WNORM(6) WNORM(7) WNORM(8) WNORM(9) WNORM(10)
#undef WNORM

  const f32x4 zf = {0.f, 0.f, 0.f, 0.f};

  // shared banded weight fragment: W[k][i] = w[k-i-3] (B in H, A in V)
  h8 Wf;
  {
    const int kb = 8 * s;
    float b0,b1,b2,b3,b4,b5,b6,b7;
    SELW(b0, kb + 0 - n - 3) SELW(b1, kb + 1 - n - 3)
    SELW(b2, kb + 2 - n - 3) SELW(b3, kb + 3 - n - 3)
    SELW(b4, kb + 4 - n - 3) SELW(b5, kb + 5 - n - 3)
    SELW(b6, kb + 6 - n - 3) SELW(b7, kb + 7 - n - 3)
    PACK8(Wf, b0,b1,b2,b3,b4,b5,b6,b7)
  }

  // H raw-tap window: cols C0-8+8s..+7; fully-outside groups weight-killed
  const int cb = C0 - 8 + 8 * s;
  const bool kill = (cb < 0) || (cb >= WW);
  h8 WfH = Wf;
  if (kill) WfH = (h8)(_Float16)0.f;
  const int ca = kill ? 0 : cb;

  const int wByte = n * 48 + 8 * s;                    // store: col n, rows 4s..4s+3
  const int rByte = n * 48 + 16 * ((s + 1) & 1);       // read: col n, rowbase {8,0,8,0}

  // zero-slot init (slot 4, all 5 quantities)
  #pragma unroll
  for (int q = 0; q < 5; ++q)
    #pragma unroll
    for (int j = 0; j < 3; ++j)
      *(unsigned*)(lds + q * Q_B + 4 * SLOT_B + 4 * (l + 64 * j)) = 0u;

  float acc0 = 0.f, acc1 = 0.f, acc2 = 0.f, acc3 = 0.f;

  // raw register sets: E = even chunks, O = odd chunks; two of each (prefetch d=2)
  v4f EXA0, EXB0, EYA0, EYB0, EXA1, EXB1, EYA1, EYB1;
  v4f OXA0, OXB0, OYA0, OYB0, OXA1, OXB1, OYA1, OYB1;

  // prologue: chunk 0 -> E0, chunk 1 -> O0; streaming pointers start at chunk 2
  EXA0 = *(const v4f*)(xp + n * WW + ca);
  EXB0 = *(const v4f*)(xp + n * WW + ca + 4);
  EYA0 = *(const v4f*)(yp + n * WW + ca);
  EYB0 = *(const v4f*)(yp + n * WW + ca + 4);
  OXA0 = *(const v4f*)(xp + (16 + n) * WW + ca);
  OXB0 = *(const v4f*)(xp + (16 + n) * WW + ca + 4);
  OYA0 = *(const v4f*)(yp + (16 + n) * WW + ca);
  OYB0 = *(const v4f*)(yp + (16 + n) * WW + ca + 4);
  const float* pXa = xp + (32 + n) * WW + ca;
  const float* pXb = pXa + 4;
  const float* pYa = yp + (32 + n) * WW + ca;
  const float* pYb = pYa + 4;

  // u=0 peeled: H(0), H(1), V(0)  (V(-1) doesn't exist)
  HSTEP(0, EXA0,EXB0,EYA0,EYB0, EXA1,EXB1,EYA1,EYB1)
  HSTEP(1, OXA0,OXB0,OYA0,OYB0, OXA1,OXB1,OYA1,OYB1)
  VSTEP(0)

  // u = 1..14 (7 double-iterations): per u -> H(2u), H(2u+1), V(2u-1), V(2u).
  // The two H-chains and two V-chains are mutually independent -> 2x ILP.
  #pragma unroll 1
  for (int w = 0; w < 7; ++w) {
    const int u1 = 2 * w + 1;         // odd u: consume set1, load set0
    HSTEP(2 * u1,     EXA1,EXB1,EYA1,EYB1, EXA0,EXB0,EYA0,EYB0)
    HSTEP(2 * u1 + 1, OXA1,OXB1,OYA1,OYB1, OXA0,OXB0,OYA0,OYB0)
    VSTEP(2 * u1 - 1)
    VSTEP(2 * u1)
    const int u2 = 2 * w + 2;         // even u: consume set0, load set1
    HSTEP(2 * u2,     EXA0,EXB0,EYA0,EYB0, EXA1,EXB1,EYA1,EYB1)
    HSTEP(2 * u2 + 1, OXA0,OXB0,OYA0,OYB0, OXA1,OXB1,OYA1,OYB1)
    VSTEP(2 * u2 - 1)
    VSTEP(2 * u2)
  }
  // u=15 (odd): H(30), H(31), V(29), V(30); tail V(31)
  HSTEP(30, EXA1,EXB1,EYA1,EYB1, EXA0,EXB0,EYA0,EYB0)
  HSTEP(31, OXA1,OXB1,OYA1,OYB1, OXA0,OXB0,OYA0,OYB0)
  VSTEP(29)
  VSTEP(30)
  VSTEP(31)

  // wave reduction -> per-block partial
  float acc = (acc0 + acc1) + (acc2 + acc3);
  #pragma unroll
  for (int off = 32; off > 0; off >>= 1) acc += __shfl_down(acc, off);
  if (l == 0) partial[wg] = acc;
}

__global__ void finalize_kernel(const float* __restrict__ partial, float* __restrict__ out)
{
  __shared__ float s4[4];
  float a = 0.f;
  for (int i = threadIdx.x; i < NBLK; i += 256) a += partial[i];
  #pragma unroll
  for (int off = 32; off > 0; off >>= 1) a += __shfl_down(a, off);
  if ((threadIdx.x & 63) == 0) s4[threadIdx.x >> 6] = a;
  __syncthreads();
  if (threadIdx.x == 0) out[0] = 1.f - (s4[0] + s4[1] + s4[2] + s4[3]) * (1.f / NPIX);
}

extern "C" void kernel_launch(void* const* d_in, const int* in_sizes, int n_in,
                              void* d_out, int out_size, void* d_ws, size_t ws_size,
                              hipStream_t stream)
{
  const float* x = (const float*)d_in[0];
  const float* y = (const float*)d_in[1];
  float* ws = (float*)d_ws;
  float* out = (float*)d_out;

  hipLaunchKernelGGL(ssim_main, dim3(NBLK), dim3(64), 0, stream, x, y, ws);
  hipLaunchKernelGGL(finalize_kernel, dim3(1), dim3(256), 0, stream, ws, out);
}